// Round 1
// baseline (338.469 us; speedup 1.0000x reference)
//
#include <hip/hip_runtime.h>
#include <cstddef>
#include <cstdint>

// MinGRU: g/v/d = x@W{g,v,d}^T + b; xs = sigmoid(g)*tanh(v); a = 0.001+0.998*sigmoid(d)
// h_t = a_t*h_{t-1} + xs_t (causal scan over S). Output h [B,S,D] f32.
// B=4, S=4096, D=1024.

typedef _Float16 f16;
typedef f16 f16x4 __attribute__((ext_vector_type(4)));
typedef f16 f16x8 __attribute__((ext_vector_type(8)));
typedef float f32x4 __attribute__((ext_vector_type(4)));

#define S_LEN 4096
#define D_DIM 1024
#define B_DIM 4
#define M_TOT (B_DIM * S_LEN)  // 16384
#define N_TOT (3 * D_DIM)      // 3072
#define K_TOT D_DIM            // 1024

#define CHUNKS 128
#define CLEN (S_LEN / CHUNKS)  // 32

// ---------------- f32 -> f16 convert, 8 elems/thread ----------------
__global__ void cvt_f16_kernel(const float* __restrict__ src, f16* __restrict__ dst, int n) {
  int i = (blockIdx.x * blockDim.x + threadIdx.x) * 8;
  if (i >= n) return;
  f32x4 a = *(const f32x4*)(src + i);
  f32x4 b = *(const f32x4*)(src + i + 4);
  f16x8 o;
  o[0] = (f16)a[0]; o[1] = (f16)a[1]; o[2] = (f16)a[2]; o[3] = (f16)a[3];
  o[4] = (f16)b[0]; o[5] = (f16)b[1]; o[6] = (f16)b[2]; o[7] = (f16)b[3];
  *(f16x8*)(dst + i) = o;
}

// ---------------- GEMM: C[M,N] = A[M,K] * Bt[N,K]^T, fp16 in, fp16 out ----------------
#define BM 128
#define BN 128
#define BK 32

__device__ __forceinline__ void gl_lds16(const void* g, void* l) {
  __builtin_amdgcn_global_load_lds((const __attribute__((address_space(1))) void*)g,
                                   (__attribute__((address_space(3))) void*)l, 16, 0, 0);
}

__global__ __launch_bounds__(256) void gemm_f16_kernel(const f16* __restrict__ A,
                                                       const f16* __restrict__ Bt,
                                                       f16* __restrict__ C) {
  __shared__ __attribute__((aligned(16))) f16 As[BM * BK];
  __shared__ __attribute__((aligned(16))) f16 Bs[BN * BK];
  const int tid = threadIdx.x;
  const int lane = tid & 63;
  const int wave = tid >> 6;
  const int m0 = blockIdx.y * BM;
  const int n0 = blockIdx.x * BN;

  // staging: round0 -> tile bytes [tid*16], round1 -> [4096 + tid*16]
  const int srow = tid >> 2;       // 0..63
  const int scol = (tid & 3) * 8;  // half index within row (row = 32 halves = 64B)
  const f16* aG0 = A + (size_t)(m0 + srow) * K_TOT + scol;
  const f16* aG1 = A + (size_t)(m0 + srow + 64) * K_TOT + scol;
  const f16* bG0 = Bt + (size_t)(n0 + srow) * K_TOT + scol;
  const f16* bG1 = Bt + (size_t)(n0 + srow + 64) * K_TOT + scol;
  f16* aL0 = &As[tid * 8];
  f16* aL1 = &As[2048 + tid * 8];
  f16* bL0 = &Bs[tid * 8];
  f16* bL1 = &Bs[2048 + tid * 8];

  const int wm = (wave >> 1) * 64;
  const int wn = (wave & 1) * 64;
  const int lm = lane & 15;
  const int kq = (lane >> 4) * 8;

  f32x4 acc[4][4] = {};

  for (int k0 = 0; k0 < K_TOT; k0 += BK) {
    gl_lds16(aG0 + k0, aL0);
    gl_lds16(aG1 + k0, aL1);
    gl_lds16(bG0 + k0, bL0);
    gl_lds16(bG1 + k0, bL1);
    __syncthreads();  // drains vmcnt -> staging visible
    f16x8 af[4], bf[4];
#pragma unroll
    for (int i = 0; i < 4; ++i)
      af[i] = *(const f16x8*)&As[(wm + i * 16 + lm) * BK + kq];
#pragma unroll
    for (int j = 0; j < 4; ++j)
      bf[j] = *(const f16x8*)&Bs[(wn + j * 16 + lm) * BK + kq];
#pragma unroll
    for (int i = 0; i < 4; ++i)
#pragma unroll
      for (int j = 0; j < 4; ++j)
        acc[i][j] = __builtin_amdgcn_mfma_f32_16x16x32_f16(af[i], bf[j], acc[i][j], 0, 0, 0);
    __syncthreads();  // protect LDS before next stage
  }

  // epilogue: C/D layout col = lane&15, row = (lane>>4)*4 + reg (m89-verified)
  const int cm = m0 + wm + (lane >> 4) * 4;
  const int cn = n0 + wn + (lane & 15);
#pragma unroll
  for (int i = 0; i < 4; ++i)
#pragma unroll
    for (int j = 0; j < 4; ++j)
#pragma unroll
      for (int r = 0; r < 4; ++r)
        C[(size_t)(cm + i * 16 + r) * N_TOT + (cn + j * 16)] = (f16)acc[i][j][r];
}

// ---------------- scan pass 1: activations + per-chunk local scan ----------------
// thread handles 4 channels x 1 chunk; u = [ck:7][b:2][cg:8]
__global__ void scan1_kernel(const f16* __restrict__ G, const float* __restrict__ bg,
                             const float* __restrict__ bv, const float* __restrict__ bd,
                             f16* __restrict__ xsA, f16* __restrict__ aA,
                             float* __restrict__ P, float* __restrict__ H) {
  const int u = blockIdx.x * 256 + threadIdx.x;
  const int cg = u & 255;
  const int b = (u >> 8) & 3;
  const int ck = u >> 10;
  const int ch = cg * 4;
  const f32x4 vbg = *(const f32x4*)(bg + ch);
  const f32x4 vbv = *(const f32x4*)(bv + ch);
  const f32x4 vbd = *(const f32x4*)(bd + ch);
  f32x4 h = {0.f, 0.f, 0.f, 0.f};
  f32x4 p = {1.f, 1.f, 1.f, 1.f};
  const int t0 = ck * CLEN;
#pragma unroll 4
  for (int t = t0; t < t0 + CLEN; ++t) {
    const size_t m = (size_t)b * S_LEN + t;
    const f16* gp = G + m * N_TOT + ch;
    f16x4 g4 = *(const f16x4*)gp;
    f16x4 v4 = *(const f16x4*)(gp + D_DIM);
    f16x4 d4 = *(const f16x4*)(gp + 2 * D_DIM);
    f16x4 xs4, a4;
#pragma unroll
    for (int j = 0; j < 4; ++j) {
      float gg = (float)g4[j] + vbg[j];
      float vv = (float)v4[j] + vbv[j];
      float dd = (float)d4[j] + vbd[j];
      float sg = 1.f / (1.f + __expf(-gg));
      float tv = 1.f - 2.f / (__expf(2.f * vv) + 1.f);
      float sd = 1.f / (1.f + __expf(-dd));
      f16 xh = (f16)(sg * tv);
      f16 ah = (f16)(0.001f + 0.998f * sd);
      // use the ROUNDED values so pass-2/3 recomposition is exactly consistent
      float xsr = (float)xh, avr = (float)ah;
      h[j] = avr * h[j] + xsr;
      p[j] *= avr;
      xs4[j] = xh;
      a4[j] = ah;
    }
    *(f16x4*)(xsA + m * D_DIM + ch) = xs4;
    *(f16x4*)(aA + m * D_DIM + ch) = a4;
  }
  const int idx = ck * 4096 + b * D_DIM + ch;
  *(f32x4*)(P + idx) = p;
  *(f32x4*)(H + idx) = h;
}

// ---------------- scan pass 2: chain carries across chunks ----------------
__global__ void scan2_kernel(const float* __restrict__ P, const float* __restrict__ H,
                             float* __restrict__ carry) {
  const int idx = blockIdx.x * 256 + threadIdx.x;  // 0..4095 = b*1024+ch
  float h = 0.f;
  for (int c = 0; c < CHUNKS; ++c) {
    carry[c * 4096 + idx] = h;
    h = P[c * 4096 + idx] * h + H[c * 4096 + idx];
  }
}

// ---------------- scan pass 3: rescan with carry, write output ----------------
__global__ void scan3_kernel(const f16* __restrict__ xsA, const f16* __restrict__ aA,
                             const float* __restrict__ carry, float* __restrict__ out) {
  const int u = blockIdx.x * 256 + threadIdx.x;
  const int cg = u & 255;
  const int b = (u >> 8) & 3;
  const int ck = u >> 10;
  const int ch = cg * 4;
  f32x4 h = *(const f32x4*)(carry + ck * 4096 + b * D_DIM + ch);
  const int t0 = ck * CLEN;
#pragma unroll 4
  for (int t = t0; t < t0 + CLEN; ++t) {
    const size_t m = (size_t)b * S_LEN + t;
    f16x4 xs4 = *(const f16x4*)(xsA + m * D_DIM + ch);
    f16x4 a4 = *(const f16x4*)(aA + m * D_DIM + ch);
#pragma unroll
    for (int j = 0; j < 4; ++j) h[j] = (float)a4[j] * h[j] + (float)xs4[j];
    *(f32x4*)(out + m * D_DIM + ch) = h;
  }
}

extern "C" void kernel_launch(void* const* d_in, const int* in_sizes, int n_in,
                              void* d_out, int out_size, void* d_ws, size_t ws_size,
                              hipStream_t stream) {
  const float* x = (const float*)d_in[0];
  const float* Wg = (const float*)d_in[1];
  const float* bg = (const float*)d_in[2];
  const float* Wv = (const float*)d_in[3];
  const float* bv = (const float*)d_in[4];
  const float* Wd = (const float*)d_in[5];
  const float* bd = (const float*)d_in[6];
  float* out = (float*)d_out;

  // workspace layout (total 213,909,504 B ~ 204 MB)
  char* ws = (char*)d_ws;
  f16* Ah = (f16*)(ws);                     // x as f16: 33,554,432 B
  f16* Bh = (f16*)(ws + 33554432);          // [Wg;Wv;Wd] as f16: 6,291,456 B
  f16* Gh = (f16*)(ws + 39845888);          // G [16384,3072] f16: 100,663,296 B
  f16* xsA = (f16*)(ws + 140509184);        // 33,554,432 B
  f16* aA = (f16*)(ws + 174063616);         // 33,554,432 B
  float* P = (float*)(ws + 207618048);      // 2,097,152 B
  float* H = (float*)(ws + 209715200);      // 2,097,152 B
  float* carry = (float*)(ws + 211812352);  // 2,097,152 B

  cvt_f16_kernel<<<8192, 256, 0, stream>>>(x, Ah, M_TOT * K_TOT);
  cvt_f16_kernel<<<512, 256, 0, stream>>>(Wg, Bh, D_DIM * D_DIM);
  cvt_f16_kernel<<<512, 256, 0, stream>>>(Wv, Bh + D_DIM * D_DIM, D_DIM * D_DIM);
  cvt_f16_kernel<<<512, 256, 0, stream>>>(Wd, Bh + 2 * D_DIM * D_DIM, D_DIM * D_DIM);
  gemm_f16_kernel<<<dim3(N_TOT / BN, M_TOT / BM), 256, 0, stream>>>(Ah, Bh, Gh);
  scan1_kernel<<<512, 256, 0, stream>>>(Gh, bg, bv, bd, xsA, aA, P, H);
  scan2_kernel<<<16, 256, 0, stream>>>(P, H, carry);
  scan3_kernel<<<512, 256, 0, stream>>>(xsA, aA, carry, out);
}